// Round 3
// baseline (12580.724 us; speedup 1.0000x reference)
//
#include <hip/hip_runtime.h>
#include <hip/hip_fp16.h>
#include <math.h>

// ---------------- problem constants ----------------
#define D_     256
#define H_     4
#define NH     8192      // N / H
#define NTOT   32768
#define T_     1024
#define B_     2
#define ROWS   2048      // B * T
#define VOCAB_ 256
#define LAYERS 6
#define EPS_   1e-5f

typedef _Float16 f16;
typedef __attribute__((ext_vector_type(8))) _Float16 f16x8;
typedef __attribute__((ext_vector_type(4))) float f32x4;

// ---------------- GEMM core: C = A (MxK) * Bt (NxK)^T ----------------
// 128x128 tile, BK=64, 256 threads = 4 waves in 2x2, each wave 64x64 via
// 4x4 frags of mfma_f32_16x16x32_f16. LDS padded +8 f16 (16B) per row.
#define BM 128
#define BN 128
#define BK 64
#define LDST (BK + 8)

#define EPI_F32      0
#define EPI_RELU     1   // relu -> f16
#define EPI_MASK     2   // keep col<row (strict causal) -> f16
#define EPI_RELU_MUL 3   // relu * aux -> f16 (in-place safe: aux may == C)
#define EPI_F32_ATOM 4   // atomicAdd f32 (split-K)

// rope on 8 packed f16 (4 pairs) with interleaved {cos,sin} f16 table vec
__device__ __forceinline__ uint4 rope8(uint4 xin, uint4 csin) {
    union U { uint4 v; f16 h[8]; };
    U x, cs, o;
    x.v = xin; cs.v = csin;
#pragma unroll
    for (int j = 0; j < 4; j++) {
        float x1 = (float)x.h[2 * j], x2 = (float)x.h[2 * j + 1];
        float c  = (float)cs.h[2 * j], s = (float)cs.h[2 * j + 1];
        o.h[2 * j]     = (f16)(x1 * c - x2 * s);
        o.h[2 * j + 1] = (f16)(x1 * s + x2 * c);
    }
    return o.v;
}

template<int EPI, bool ROPE>
__device__ __forceinline__ void gemm_core(
    const f16* __restrict__ A, int lda,
    const f16* __restrict__ Bt, int ldb,
    void* __restrict__ Cv, int ldc,
    int k_end, const f16* __restrict__ aux,
    const f16* __restrict__ cstab)
{
    __shared__ f16 As[BM * LDST];
    __shared__ f16 Bs[BN * LDST];

    const int tid  = threadIdx.x;
    const int lane = tid & 63;
    const int wid  = tid >> 6;
    const int wr   = (wid >> 1) * 64;
    const int wc   = (wid & 1) * 64;
    const int lr   = lane & 15;
    const int lk   = (lane >> 4) * 8;

    const int row0 = blockIdx.y * BM;
    const int col0 = blockIdx.x * BN;

    f32x4 acc[4][4];
#pragma unroll
    for (int m = 0; m < 4; m++)
#pragma unroll
        for (int n = 0; n < 4; n++) acc[m][n] = (f32x4){0.f, 0.f, 0.f, 0.f};

    for (int k0 = 0; k0 < k_end; k0 += BK) {
        // stage A and Bt tiles: 1024 16B-vectors each, 4 per thread
#pragma unroll
        for (int i = 0; i < 4; i++) {
            int v  = tid + i * 256;
            int r  = v >> 3;
            int c8 = (v & 7) << 3;
            uint4 av = *(const uint4*)(A  + (size_t)(row0 + r) * lda + k0 + c8);
            uint4 bv = *(const uint4*)(Bt + (size_t)(col0 + r) * ldb + k0 + c8);
            if constexpr (ROPE) {
                // for the score GEMM: A-row index == t, Bt-row index == s,
                // column index == n within the head; pair index p = n/2.
                int p = (k0 + c8) >> 1;
                av = rope8(av, *(const uint4*)(cstab + ((size_t)(row0 + r) * 4096 + p) * 2));
                bv = rope8(bv, *(const uint4*)(cstab + ((size_t)(col0 + r) * 4096 + p) * 2));
            }
            *(uint4*)(&As[r * LDST + c8]) = av;
            *(uint4*)(&Bs[r * LDST + c8]) = bv;
        }
        __syncthreads();
#pragma unroll
        for (int kk = 0; kk < BK; kk += 32) {
            f16x8 af[4], bfr[4];
#pragma unroll
            for (int m = 0; m < 4; m++)
                af[m] = *(const f16x8*)(&As[(wr + m * 16 + lr) * LDST + kk + lk]);
#pragma unroll
            for (int n = 0; n < 4; n++)
                bfr[n] = *(const f16x8*)(&Bs[(wc + n * 16 + lr) * LDST + kk + lk]);
#pragma unroll
            for (int m = 0; m < 4; m++)
#pragma unroll
                for (int n = 0; n < 4; n++)
                    acc[m][n] = __builtin_amdgcn_mfma_f32_16x16x32_f16(
                        af[m], bfr[n], acc[m][n], 0, 0, 0);
        }
        __syncthreads();
    }

    // epilogue: C row = A row, C col = Bt row; col=lane&15, row=(lane>>4)*4+r
    const int rbase = (lane >> 4) * 4;
#pragma unroll
    for (int m = 0; m < 4; m++) {
#pragma unroll
        for (int n = 0; n < 4; n++) {
#pragma unroll
            for (int r = 0; r < 4; r++) {
                int row = row0 + wr + m * 16 + rbase + r;
                int col = col0 + wc + n * 16 + lr;
                float val = acc[m][n][r];
                size_t o = (size_t)row * ldc + col;
                if constexpr (EPI == EPI_F32) {
                    ((float*)Cv)[o] = val;
                } else if constexpr (EPI == EPI_RELU) {
                    ((f16*)Cv)[o] = (f16)(val > 0.f ? val : 0.f);
                } else if constexpr (EPI == EPI_MASK) {
                    ((f16*)Cv)[o] = (f16)(col < row ? val : 0.f);
                } else if constexpr (EPI == EPI_RELU_MUL) {
                    float xv = (float)aux[o];
                    ((f16*)Cv)[o] = (f16)((val > 0.f ? val : 0.f) * xv);
                } else { // EPI_F32_ATOM
                    atomicAdd(((float*)Cv) + o, val);
                }
            }
        }
    }
}

// ---------------- GEMM wrappers (per-head streaming) ----------------
// x_h = relu(vb @ dxT_h^T)  [ROWS][NH]
__global__ __launch_bounds__(256) void k_gemm_x(const f16* __restrict__ vb,
                                                const f16* __restrict__ dxTh,
                                                f16* __restrict__ xh)
{
    gemm_core<EPI_RELU, false>(vb, D_, dxTh, D_, xh, NH, D_, nullptr, nullptr);
}

// S = rope(x_h) rope(x_h)^T, strictly-causal masked; rope fused in staging
__global__ __launch_bounds__(256) void k_gemm_s(const f16* __restrict__ xh,
                                                f16* __restrict__ S,
                                                const f16* __restrict__ cstab)
{
    if (blockIdx.x > blockIdx.y) return;  // upper tiles never written, never read
    int b = blockIdx.z;
    const f16* Ab = xh + (size_t)b * T_ * NH;
    gemm_core<EPI_MASK, true>(Ab, NH, Ab, NH,
                              S + (size_t)b * T_ * T_, T_, NH, nullptr, cstab);
}

// a_h = S @ v  [ROWS][D]
__global__ __launch_bounds__(256) void k_gemm_a(const f16* __restrict__ S,
                                                const f16* __restrict__ vT,
                                                float* __restrict__ ah)
{
    int b = blockIdx.z;
    int kend = (blockIdx.y + 1) * BM;  // rows t in this tile need only s < kend
    gemm_core<EPI_F32, false>(S + (size_t)b * T_ * T_, T_,
                              vT + (size_t)b * D_ * T_, T_,
                              ah + (size_t)b * T_ * D_, D_, kend, nullptr, nullptr);
}

// y_h = relu(lnA_h @ dyT_h^T) * x_h, written IN-PLACE over x_h
__global__ __launch_bounds__(256) void k_gemm_y(const f16* __restrict__ lnAh,
                                                const f16* __restrict__ dyTh,
                                                f16* __restrict__ xh)
{
    gemm_core<EPI_RELU_MUL, false>(lnAh, D_, dyTh, D_, xh, NH, D_, xh, nullptr);
}

// zb += y_h @ enc_h  (split-K=2, f32 atomic accumulate across heads too)
__global__ __launch_bounds__(256) void k_gemm_z(const f16* __restrict__ yh,
                                                const f16* __restrict__ encTh,
                                                float* __restrict__ zb)
{
    int kc = blockIdx.z;
    gemm_core<EPI_F32_ATOM, false>(yh + kc * 4096, NH, encTh + kc * 4096, NTOT,
                                   zb, D_, 4096, nullptr, nullptr);
}

// ---------------- elementwise / LN / transpose ----------------
__device__ __forceinline__ float wave_sum(float s) {
#pragma unroll
    for (int off = 32; off; off >>= 1) s += __shfl_xor(s, off);
    return s;
}

__device__ __forceinline__ float4 ln4(float4 x) {
    float m = wave_sum(x.x + x.y + x.z + x.w) * (1.f / 256.f);
    float d0 = x.x - m, d1 = x.y - m, d2 = x.z - m, d3 = x.w - m;
    float var = wave_sum(d0 * d0 + d1 * d1 + d2 * d2 + d3 * d3) * (1.f / 256.f);
    float rs = rsqrtf(var + EPS_);
    return make_float4(d0 * rs, d1 * rs, d2 * rs, d3 * rs);
}

__device__ __forceinline__ void store_v_row(float4 o, int row, int lane,
                                            float* v, f16* vb, f16* vT) {
    *(float4*)(v + (size_t)row * D_ + lane * 4) = o;
    union { unsigned long long u; f16 h[4]; } p;
    p.h[0] = (f16)o.x; p.h[1] = (f16)o.y; p.h[2] = (f16)o.z; p.h[3] = (f16)o.w;
    *(unsigned long long*)(vb + (size_t)row * D_ + lane * 4) = p.u;
    int b = row >> 10, t = row & (T_ - 1);
    f16* vtp = vT + ((size_t)b * D_ + lane * 4) * T_ + t;
    vtp[0] = p.h[0]; vtp[T_] = p.h[1]; vtp[2 * T_] = p.h[2]; vtp[3 * T_] = p.h[3];
}

__global__ __launch_bounds__(256) void k_embed_ln(const int* __restrict__ idx,
                                                  const float* __restrict__ wte,
                                                  float* __restrict__ v,
                                                  f16* __restrict__ vb,
                                                  f16* __restrict__ vT)
{
    int row = blockIdx.x * 4 + (threadIdx.x >> 6);
    int lane = threadIdx.x & 63;
    int tok = idx[row];
    float4 x = *(const float4*)(wte + (size_t)tok * D_ + lane * 4);
    store_v_row(ln4(x), row, lane, v, vb, vT);
}

__global__ __launch_bounds__(256) void k_ln_f16(const float* __restrict__ in,
                                                f16* __restrict__ out)
{
    int row = blockIdx.x * 4 + (threadIdx.x >> 6);
    int lane = threadIdx.x & 63;
    float4 x = *(const float4*)(in + (size_t)row * D_ + lane * 4);
    float4 o = ln4(x);
    union { unsigned long long u; f16 h[4]; } p;
    p.h[0] = (f16)o.x; p.h[1] = (f16)o.y; p.h[2] = (f16)o.z; p.h[3] = (f16)o.w;
    *(unsigned long long*)(out + (size_t)row * D_ + lane * 4) = p.u;
}

__global__ __launch_bounds__(256) void k_update(const float* __restrict__ z,
                                                float* __restrict__ v,
                                                f16* __restrict__ vb,
                                                f16* __restrict__ vT)
{
    int row = blockIdx.x * 4 + (threadIdx.x >> 6);
    int lane = threadIdx.x & 63;
    float4 zr = *(const float4*)(z + (size_t)row * D_ + lane * 4);
    float4 lz = ln4(zr);
    float4 vr = *(const float4*)(v + (size_t)row * D_ + lane * 4);
    float4 u = make_float4(vr.x + lz.x, vr.y + lz.y, vr.z + lz.z, vr.w + lz.w);
    store_v_row(ln4(u), row, lane, v, vb, vT);
}

// interleaved {cos,sin} f16 table: [T][4096 pairs][2]
__global__ __launch_bounds__(256) void k_tables(f16* __restrict__ cstab)
{
    int i = blockIdx.x * 256 + threadIdx.x;   // T_ * 4096 total
    int t = i >> 12;
    int f = i & 4095;
    float invf = expf(-(float)f * (9.210340371976184f / 4096.f));
    float s, c;
    sincosf((float)t * invf, &s, &c);
    cstab[2 * i]     = (f16)c;
    cstab[2 * i + 1] = (f16)s;
}

// in: f32 [R][C] (batched) -> out: f16 [C][R]
__global__ void k_transpose(const float* __restrict__ in, f16* __restrict__ out,
                            int R, int C, size_t inBatch, size_t outBatch)
{
    const float* ip = in + (size_t)blockIdx.z * inBatch;
    f16* op = out + (size_t)blockIdx.z * outBatch;
    __shared__ float tile[32][33];
    int c0 = blockIdx.x * 32, r0 = blockIdx.y * 32;
    int tx = threadIdx.x, ty = threadIdx.y;
#pragma unroll
    for (int i = 0; i < 32; i += 8)
        tile[ty + i][tx] = ip[(size_t)(r0 + ty + i) * C + c0 + tx];
    __syncthreads();
#pragma unroll
    for (int i = 0; i < 32; i += 8)
        op[(size_t)(c0 + ty + i) * R + r0 + tx] = (f16)tile[tx][ty + i];
}

__global__ __launch_bounds__(256) void k_readout(const float* __restrict__ v,
                                                 const float* __restrict__ ro,
                                                 float* __restrict__ out)
{
    int row = blockIdx.x;
    int tid = threadIdx.x;
    __shared__ float vr[D_];
    vr[tid] = v[(size_t)row * D_ + tid];
    __syncthreads();
    float acc = 0.f;
#pragma unroll 8
    for (int d = 0; d < D_; d++) acc += vr[d] * ro[(size_t)d * VOCAB_ + tid];
    out[(size_t)row * VOCAB_ + tid] = acc;
}

// diagnostic: encode ws_size into output if workspace is insufficient
__global__ void k_sentinel(float* out, float val) { out[0] = val; }

// ---------------- launch ----------------
extern "C" void kernel_launch(void* const* d_in, const int* in_sizes, int n_in,
                              void* d_out, int out_size, void* d_ws, size_t ws_size,
                              hipStream_t stream)
{
    const int*   idx = (const int*)d_in[0];
    const float* wte = (const float*)d_in[1];
    const float* enc = (const float*)d_in[2];
    const float* dx  = (const float*)d_in[3];
    const float* dy  = (const float*)d_in[4];
    const float* ro  = (const float*)d_in[5];
    float* out = (float*)d_out;

    char* base = (char*)d_ws;
    size_t off = 0;
    auto alloc = [&](size_t bytes) -> void* {
        off = (off + 255) & ~(size_t)255;
        void* r = base + off;
        off += bytes;
        return r;
    };

    f16*   dxT   = (f16*)  alloc((size_t)H_ * NH * D_ * 2);     // 16 MB
    f16*   dyT   = (f16*)  alloc((size_t)H_ * NH * D_ * 2);     // 16 MB
    f16*   encT  = (f16*)  alloc((size_t)D_ * NTOT * 2);        // 16 MB
    f16*   cstab = (f16*)  alloc((size_t)T_ * 4096 * 2 * 2);    // 16 MB
    float* v     = (float*)alloc((size_t)ROWS * D_ * 4);        //  2 MB
    f16*   vb    = (f16*)  alloc((size_t)ROWS * D_ * 2);        //  1 MB
    f16*   vT    = (f16*)  alloc((size_t)B_ * D_ * T_ * 2);     //  1 MB
    f16*   xh    = (f16*)  alloc((size_t)ROWS * NH * 2);        // 32 MB
    f16*   S     = (f16*)  alloc((size_t)B_ * T_ * T_ * 2);     //  4 MB
    float* ah    = (float*)alloc((size_t)ROWS * D_ * 4);        //  2 MB
    f16*   lnAh  = (f16*)  alloc((size_t)ROWS * D_ * 2);        //  1 MB
    float* zb    = (float*)alloc((size_t)ROWS * D_ * 4);        //  2 MB
    // total ~109 MB
    if (off > ws_size) {
        k_sentinel<<<1, 1, 0, stream>>>(out, 10000.f + (float)(ws_size >> 20));
        return;
    }

    dim3 blk(256), tb(32, 8);

    k_transpose<<<dim3(NH / 32, D_ / 32, H_), tb, 0, stream>>>(
        dx, dxT, D_, NH, (size_t)D_ * NH, (size_t)NH * D_);
    k_transpose<<<dim3(NH / 32, D_ / 32, H_), tb, 0, stream>>>(
        dy, dyT, D_, NH, (size_t)D_ * NH, (size_t)NH * D_);
    k_transpose<<<dim3(D_ / 32, NTOT / 32, 1), tb, 0, stream>>>(
        enc, encT, NTOT, D_, 0, 0);
    k_tables<<<T_ * 4096 / 256, blk, 0, stream>>>(cstab);
    k_embed_ln<<<ROWS / 4, blk, 0, stream>>>(idx, wte, v, vb, vT);

    for (int l = 0; l < LAYERS; l++) {
        hipMemsetAsync(zb, 0, (size_t)ROWS * D_ * 4, stream);
        for (int h = 0; h < H_; h++) {
            const f16* dxTh = dxT + (size_t)h * NH * D_;
            const f16* dyTh = dyT + (size_t)h * NH * D_;
            const f16* encTh = encT + (size_t)h * NH;
            k_gemm_x<<<dim3(NH / BN, ROWS / BM), blk, 0, stream>>>(vb, dxTh, xh);
            k_gemm_s<<<dim3(T_ / BN, T_ / BM, B_), blk, 0, stream>>>(xh, S, cstab);
            k_gemm_a<<<dim3(D_ / BN, T_ / BM, B_), blk, 0, stream>>>(S, vT, ah);
            k_ln_f16<<<ROWS / 4, blk, 0, stream>>>(ah, lnAh);
            k_gemm_y<<<dim3(NH / BN, ROWS / BM), blk, 0, stream>>>(lnAh, dyTh, xh);
            k_gemm_z<<<dim3(D_ / BN, ROWS / BM, 2), blk, 0, stream>>>(xh, encTh, zb);
        }
        k_update<<<ROWS / 4, blk, 0, stream>>>(zb, v, vb, vT);
    }
    k_readout<<<ROWS, blk, 0, stream>>>(v, ro, out);
}

// Round 4
// 6108.047 us; speedup vs baseline: 2.0597x; 2.0597x over previous
//
#include <hip/hip_runtime.h>
#include <hip/hip_fp16.h>
#include <math.h>

// ---------------- problem constants ----------------
#define D_     256
#define H_     4
#define NH     8192      // N / H
#define NTOT   32768
#define T_     1024
#define B_     2
#define ROWS   2048      // B * T
#define VOCAB_ 256
#define LAYERS 6
#define EPS_   1e-5f

typedef _Float16 f16;
typedef __attribute__((ext_vector_type(8))) _Float16 f16x8;
typedef __attribute__((ext_vector_type(4))) float f32x4;

// ---------------- GEMM core: C = A (MxK) * Bt (NxK)^T ----------------
// 128x128 tile, BK=64, 256 threads = 4 waves in 2x2, each wave 64x64 via
// 4x4 frags of mfma_f32_16x16x32_f16. LDS padded +8 f16 (16B) per row.
#define BM 128
#define BN 128
#define BK 64
#define LDST (BK + 8)

#define EPI_F32      0   // plain f32 store
#define EPI_RELU     1   // relu -> f16
#define EPI_RELU_MUL 3   // relu * aux -> f16 (in-place safe: aux may == C)
#define EPI_F32_ATOM 4   // atomicAdd f32 (split-K)

// rope on 8 packed f16 (4 pairs) with interleaved {cos,sin} f16 table vec
__device__ __forceinline__ uint4 rope8(uint4 xin, uint4 csin) {
    union U { uint4 v; f16 h[8]; };
    U x, cs, o;
    x.v = xin; cs.v = csin;
#pragma unroll
    for (int j = 0; j < 4; j++) {
        float x1 = (float)x.h[2 * j], x2 = (float)x.h[2 * j + 1];
        float c  = (float)cs.h[2 * j], s = (float)cs.h[2 * j + 1];
        o.h[2 * j]     = (f16)(x1 * c - x2 * s);
        o.h[2 * j + 1] = (f16)(x1 * s + x2 * c);
    }
    return o.v;
}

// ROPE: rope A and B tiles while staging (score GEMM; A,B rows are t,s)
// ACVT: A is f32 (Sf); convert + strict-causal mask (col<row) while staging
template<int EPI, bool ROPE, bool ACVT>
__device__ __forceinline__ void gemm_core(
    const void* __restrict__ Av, int lda,
    const f16* __restrict__ Bt, int ldb,
    void* __restrict__ Cv, int ldc,
    int row0, int col0, int k0beg, int k_end,
    const f16* __restrict__ aux,
    const f16* __restrict__ cstab)
{
    __shared__ f16 As[BM * LDST];
    __shared__ f16 Bs[BN * LDST];

    const int tid  = threadIdx.x;
    const int lane = tid & 63;
    const int wid  = tid >> 6;
    const int wr   = (wid >> 1) * 64;
    const int wc   = (wid & 1) * 64;
    const int lr   = lane & 15;
    const int lk   = (lane >> 4) * 8;

    f32x4 acc[4][4];
#pragma unroll
    for (int m = 0; m < 4; m++)
#pragma unroll
        for (int n = 0; n < 4; n++) acc[m][n] = (f32x4){0.f, 0.f, 0.f, 0.f};

    for (int k0 = k0beg; k0 < k_end; k0 += BK) {
        // stage A and Bt tiles: 1024 16B-vectors each, 4 per thread
#pragma unroll
        for (int i = 0; i < 4; i++) {
            int v  = tid + i * 256;
            int r  = v >> 3;
            int c8 = (v & 7) << 3;
            uint4 av;
            if constexpr (ACVT) {
                const float* Af = (const float*)Av;
                size_t base = (size_t)(row0 + r) * lda + k0 + c8;
                float4 f0 = *(const float4*)(Af + base);
                float4 f1 = *(const float4*)(Af + base + 4);
                int colb = k0 + c8, row = row0 + r;
                float fv[8] = {f0.x, f0.y, f0.z, f0.w, f1.x, f1.y, f1.z, f1.w};
                union { uint4 v4; f16 h[8]; } u;
#pragma unroll
                for (int j = 0; j < 8; j++)
                    u.h[j] = (f16)((colb + j < row) ? fv[j] : 0.f);
                av = u.v4;
            } else {
                av = *(const uint4*)((const f16*)Av + (size_t)(row0 + r) * lda + k0 + c8);
                if constexpr (ROPE) {
                    int p = (k0 + c8) >> 1;
                    av = rope8(av, *(const uint4*)(cstab + ((size_t)(row0 + r) * 4096 + p) * 2));
                }
            }
            uint4 bv = *(const uint4*)(Bt + (size_t)(col0 + r) * ldb + k0 + c8);
            if constexpr (ROPE) {
                int p = (k0 + c8) >> 1;
                bv = rope8(bv, *(const uint4*)(cstab + ((size_t)(col0 + r) * 4096 + p) * 2));
            }
            *(uint4*)(&As[r * LDST + c8]) = av;
            *(uint4*)(&Bs[r * LDST + c8]) = bv;
        }
        __syncthreads();
#pragma unroll
        for (int kk = 0; kk < BK; kk += 32) {
            f16x8 af[4], bfr[4];
#pragma unroll
            for (int m = 0; m < 4; m++)
                af[m] = *(const f16x8*)(&As[(wr + m * 16 + lr) * LDST + kk + lk]);
#pragma unroll
            for (int n = 0; n < 4; n++)
                bfr[n] = *(const f16x8*)(&Bs[(wc + n * 16 + lr) * LDST + kk + lk]);
#pragma unroll
            for (int m = 0; m < 4; m++)
#pragma unroll
                for (int n = 0; n < 4; n++)
                    acc[m][n] = __builtin_amdgcn_mfma_f32_16x16x32_f16(
                        af[m], bfr[n], acc[m][n], 0, 0, 0);
        }
        __syncthreads();
    }

    // epilogue: C row = A row, C col = Bt row; col=lane&15, row=(lane>>4)*4+r
    const int rbase = (lane >> 4) * 4;
#pragma unroll
    for (int m = 0; m < 4; m++) {
#pragma unroll
        for (int n = 0; n < 4; n++) {
#pragma unroll
            for (int r = 0; r < 4; r++) {
                int row = row0 + wr + m * 16 + rbase + r;
                int col = col0 + wc + n * 16 + lr;
                float val = acc[m][n][r];
                size_t o = (size_t)row * ldc + col;
                if constexpr (EPI == EPI_F32) {
                    ((float*)Cv)[o] = val;
                } else if constexpr (EPI == EPI_RELU) {
                    ((f16*)Cv)[o] = (f16)(val > 0.f ? val : 0.f);
                } else if constexpr (EPI == EPI_RELU_MUL) {
                    float xv = (float)aux[o];
                    ((f16*)Cv)[o] = (f16)((val > 0.f ? val : 0.f) * xv);
                } else { // EPI_F32_ATOM
                    atomicAdd(((float*)Cv) + o, val);
                }
            }
        }
    }
}

// ---------------- GEMM wrappers (per-head streaming) ----------------
// x_h = relu(vb @ dxT_h^T)  [ROWS][NH]
__global__ __launch_bounds__(256) void k_gemm_x(const f16* __restrict__ vb,
                                                const f16* __restrict__ dxTh,
                                                f16* __restrict__ xh)
{
    gemm_core<EPI_RELU, false, false>(vb, D_, dxTh, D_, xh, NH,
                                      blockIdx.y * BM, blockIdx.x * BN,
                                      0, D_, nullptr, nullptr);
}

// Sf += rope(x_h) rope(x_h)^T chunk; packed lower-tri grid + split-K, atomics
#define KSPLIT_S 8
__global__ __launch_bounds__(256) void k_gemm_s(const f16* __restrict__ xh,
                                                float* __restrict__ Sf,
                                                const f16* __restrict__ cstab)
{
    int tb = blockIdx.x;              // b*36 + packed lower-tri tile index
    int b  = tb / 36, ti = tb % 36;
    int ty = 0;
    while ((ty + 1) * (ty + 2) / 2 <= ti) ty++;
    int tx = ti - ty * (ty + 1) / 2;  // tx <= ty
    int k0 = blockIdx.y * (NH / KSPLIT_S);
    const f16* Ab = xh + (size_t)b * T_ * NH;
    gemm_core<EPI_F32_ATOM, true, false>(Ab, NH, Ab, NH,
                                         Sf + (size_t)b * T_ * T_, T_,
                                         ty * BM, tx * BN,
                                         k0, k0 + NH / KSPLIT_S, nullptr, cstab);
}

// a_h = mask(Sf) @ v ; f32 A staged with fused cvt+mask; causal split-K
#define CH_A 128
__global__ __launch_bounds__(256) void k_gemm_a(const float* __restrict__ Sf,
                                                const f16* __restrict__ vT,
                                                float* __restrict__ ah)
{
    int b = blockIdx.z >> 3, kc = blockIdx.z & 7;
    int kend = (blockIdx.y + 1) * BM;   // rows t in this tile need only s < kend
    int k0 = kc * CH_A;
    if (k0 >= kend) return;
    gemm_core<EPI_F32_ATOM, false, true>(Sf + (size_t)b * T_ * T_, T_,
                                         vT + (size_t)b * D_ * T_, T_,
                                         ah + (size_t)b * T_ * D_, D_,
                                         blockIdx.y * BM, blockIdx.x * BN,
                                         k0, k0 + CH_A, nullptr, nullptr);
}

// y_h = relu(lnA_h @ dyT_h^T) * x_h, written IN-PLACE over x_h
__global__ __launch_bounds__(256) void k_gemm_y(const f16* __restrict__ lnAh,
                                                const f16* __restrict__ dyTh,
                                                f16* __restrict__ xh)
{
    gemm_core<EPI_RELU_MUL, false, false>(lnAh, D_, dyTh, D_, xh, NH,
                                          blockIdx.y * BM, blockIdx.x * BN,
                                          0, D_, xh, nullptr);
}

// zb += y_h @ enc_h  (split-K=16, f32 atomic accumulate across heads too)
#define KSPLIT_Z 16
__global__ __launch_bounds__(256) void k_gemm_z(const f16* __restrict__ yh,
                                                const f16* __restrict__ encTh,
                                                float* __restrict__ zb)
{
    int k0 = blockIdx.z * (NH / KSPLIT_Z);
    gemm_core<EPI_F32_ATOM, false, false>(yh, NH, encTh, NTOT, zb, D_,
                                          blockIdx.y * BM, blockIdx.x * BN,
                                          k0, k0 + NH / KSPLIT_Z, nullptr, nullptr);
}

// ---------------- elementwise / LN / transpose ----------------
__device__ __forceinline__ float wave_sum(float s) {
#pragma unroll
    for (int off = 32; off; off >>= 1) s += __shfl_xor(s, off);
    return s;
}

__device__ __forceinline__ float4 ln4(float4 x) {
    float m = wave_sum(x.x + x.y + x.z + x.w) * (1.f / 256.f);
    float d0 = x.x - m, d1 = x.y - m, d2 = x.z - m, d3 = x.w - m;
    float var = wave_sum(d0 * d0 + d1 * d1 + d2 * d2 + d3 * d3) * (1.f / 256.f);
    float rs = rsqrtf(var + EPS_);
    return make_float4(d0 * rs, d1 * rs, d2 * rs, d3 * rs);
}

__device__ __forceinline__ void store_v_row(float4 o, int row, int lane,
                                            float* v, f16* vb, f16* vT) {
    *(float4*)(v + (size_t)row * D_ + lane * 4) = o;
    union { unsigned long long u; f16 h[4]; } p;
    p.h[0] = (f16)o.x; p.h[1] = (f16)o.y; p.h[2] = (f16)o.z; p.h[3] = (f16)o.w;
    *(unsigned long long*)(vb + (size_t)row * D_ + lane * 4) = p.u;
    int b = row >> 10, t = row & (T_ - 1);
    f16* vtp = vT + ((size_t)b * D_ + lane * 4) * T_ + t;
    vtp[0] = p.h[0]; vtp[T_] = p.h[1]; vtp[2 * T_] = p.h[2]; vtp[3 * T_] = p.h[3];
}

__global__ __launch_bounds__(256) void k_embed_ln(const int* __restrict__ idx,
                                                  const float* __restrict__ wte,
                                                  float* __restrict__ v,
                                                  f16* __restrict__ vb,
                                                  f16* __restrict__ vT)
{
    int row = blockIdx.x * 4 + (threadIdx.x >> 6);
    int lane = threadIdx.x & 63;
    int tok = idx[row];
    float4 x = *(const float4*)(wte + (size_t)tok * D_ + lane * 4);
    store_v_row(ln4(x), row, lane, v, vb, vT);
}

__global__ __launch_bounds__(256) void k_ln_f16(const float* __restrict__ in,
                                                f16* __restrict__ out)
{
    int row = blockIdx.x * 4 + (threadIdx.x >> 6);
    int lane = threadIdx.x & 63;
    float4 x = *(const float4*)(in + (size_t)row * D_ + lane * 4);
    float4 o = ln4(x);
    union { unsigned long long u; f16 h[4]; } p;
    p.h[0] = (f16)o.x; p.h[1] = (f16)o.y; p.h[2] = (f16)o.z; p.h[3] = (f16)o.w;
    *(unsigned long long*)(out + (size_t)row * D_ + lane * 4) = p.u;
}

__global__ __launch_bounds__(256) void k_update(const float* __restrict__ z,
                                                float* __restrict__ v,
                                                f16* __restrict__ vb,
                                                f16* __restrict__ vT)
{
    int row = blockIdx.x * 4 + (threadIdx.x >> 6);
    int lane = threadIdx.x & 63;
    float4 zr = *(const float4*)(z + (size_t)row * D_ + lane * 4);
    float4 lz = ln4(zr);
    float4 vr = *(const float4*)(v + (size_t)row * D_ + lane * 4);
    float4 u = make_float4(vr.x + lz.x, vr.y + lz.y, vr.z + lz.z, vr.w + lz.w);
    store_v_row(ln4(u), row, lane, v, vb, vT);
}

// interleaved {cos,sin} f16 table: [T][4096 pairs][2]
__global__ __launch_bounds__(256) void k_tables(f16* __restrict__ cstab)
{
    int i = blockIdx.x * 256 + threadIdx.x;   // T_ * 4096 total
    int t = i >> 12;
    int f = i & 4095;
    float invf = expf(-(float)f * (9.210340371976184f / 4096.f));
    float s, c;
    sincosf((float)t * invf, &s, &c);
    cstab[2 * i]     = (f16)c;
    cstab[2 * i + 1] = (f16)s;
}

// in: f32 [R][C] (batched) -> out: f16 [C][R]
__global__ void k_transpose(const float* __restrict__ in, f16* __restrict__ out,
                            int R, int C, size_t inBatch, size_t outBatch)
{
    const float* ip = in + (size_t)blockIdx.z * inBatch;
    f16* op = out + (size_t)blockIdx.z * outBatch;
    __shared__ float tile[32][33];
    int c0 = blockIdx.x * 32, r0 = blockIdx.y * 32;
    int tx = threadIdx.x, ty = threadIdx.y;
#pragma unroll
    for (int i = 0; i < 32; i += 8)
        tile[ty + i][tx] = ip[(size_t)(r0 + ty + i) * C + c0 + tx];
    __syncthreads();
#pragma unroll
    for (int i = 0; i < 32; i += 8)
        op[(size_t)(c0 + ty + i) * R + r0 + tx] = (f16)tile[tx][ty + i];
}

__global__ __launch_bounds__(256) void k_readout(const float* __restrict__ v,
                                                 const float* __restrict__ ro,
                                                 float* __restrict__ out)
{
    int row = blockIdx.x;
    int tid = threadIdx.x;
    __shared__ float vr[D_];
    vr[tid] = v[(size_t)row * D_ + tid];
    __syncthreads();
    float acc = 0.f;
#pragma unroll 8
    for (int d = 0; d < D_; d++) acc += vr[d] * ro[(size_t)d * VOCAB_ + tid];
    out[(size_t)row * VOCAB_ + tid] = acc;
}

// diagnostic: encode ws_size into output if workspace is insufficient
__global__ void k_sentinel(float* out, float val) { out[0] = val; }

// ---------------- launch ----------------
extern "C" void kernel_launch(void* const* d_in, const int* in_sizes, int n_in,
                              void* d_out, int out_size, void* d_ws, size_t ws_size,
                              hipStream_t stream)
{
    const int*   idx = (const int*)d_in[0];
    const float* wte = (const float*)d_in[1];
    const float* enc = (const float*)d_in[2];
    const float* dx  = (const float*)d_in[3];
    const float* dy  = (const float*)d_in[4];
    const float* ro  = (const float*)d_in[5];
    float* out = (float*)d_out;

    char* base = (char*)d_ws;
    size_t off = 0;
    auto alloc = [&](size_t bytes) -> void* {
        off = (off + 255) & ~(size_t)255;
        void* r = base + off;
        off += bytes;
        return r;
    };

    f16*   dxT   = (f16*)  alloc((size_t)H_ * NH * D_ * 2);     // 16 MB
    f16*   dyT   = (f16*)  alloc((size_t)H_ * NH * D_ * 2);     // 16 MB
    f16*   encT  = (f16*)  alloc((size_t)D_ * NTOT * 2);        // 16 MB
    f16*   cstab = (f16*)  alloc((size_t)T_ * 4096 * 2 * 2);    // 16 MB
    float* v     = (float*)alloc((size_t)ROWS * D_ * 4);        //  2 MB
    f16*   vb    = (f16*)  alloc((size_t)ROWS * D_ * 2);        //  1 MB
    f16*   vT    = (f16*)  alloc((size_t)B_ * D_ * T_ * 2);     //  1 MB
    f16*   xh    = (f16*)  alloc((size_t)ROWS * NH * 2);        // 32 MB
    float* Sf    = (float*)alloc((size_t)B_ * T_ * T_ * 4);     //  8 MB
    float* ah    = (float*)alloc((size_t)ROWS * D_ * 4);        //  2 MB
    f16*   lnAh  = (f16*)  alloc((size_t)ROWS * D_ * 2);        //  1 MB
    float* zb    = (float*)alloc((size_t)ROWS * D_ * 4);        //  2 MB
    // total ~113 MB
    if (off > ws_size) {
        k_sentinel<<<1, 1, 0, stream>>>(out, 10000.f + (float)(ws_size >> 20));
        return;
    }

    dim3 blk(256), tb(32, 8);

    k_transpose<<<dim3(NH / 32, D_ / 32, H_), tb, 0, stream>>>(
        dx, dxT, D_, NH, (size_t)D_ * NH, (size_t)NH * D_);
    k_transpose<<<dim3(NH / 32, D_ / 32, H_), tb, 0, stream>>>(
        dy, dyT, D_, NH, (size_t)D_ * NH, (size_t)NH * D_);
    k_transpose<<<dim3(D_ / 32, NTOT / 32, 1), tb, 0, stream>>>(
        enc, encT, NTOT, D_, 0, 0);
    k_tables<<<T_ * 4096 / 256, blk, 0, stream>>>(cstab);
    k_embed_ln<<<ROWS / 4, blk, 0, stream>>>(idx, wte, v, vb, vT);

    for (int l = 0; l < LAYERS; l++) {
        hipMemsetAsync(zb, 0, (size_t)ROWS * D_ * 4, stream);
        for (int h = 0; h < H_; h++) {
            const f16* dxTh  = dxT + (size_t)h * NH * D_;
            const f16* dyTh  = dyT + (size_t)h * NH * D_;
            const f16* encTh = encT + (size_t)h * NH;
            k_gemm_x<<<dim3(NH / BN, ROWS / BM), blk, 0, stream>>>(vb, dxTh, xh);
            hipMemsetAsync(Sf, 0, (size_t)B_ * T_ * T_ * 4, stream);
            k_gemm_s<<<dim3(36 * B_, KSPLIT_S), blk, 0, stream>>>(xh, Sf, cstab);
            hipMemsetAsync(ah, 0, (size_t)ROWS * D_ * 4, stream);
            k_gemm_a<<<dim3(D_ / BN, T_ / BM, B_ * 8), blk, 0, stream>>>(Sf, vT, ah);
            k_ln_f16<<<ROWS / 4, blk, 0, stream>>>(ah, lnAh);
            k_gemm_y<<<dim3(NH / BN, ROWS / BM), blk, 0, stream>>>(lnAh, dyTh, xh);
            k_gemm_z<<<dim3(D_ / BN, ROWS / BM, KSPLIT_Z), blk, 0, stream>>>(xh, encTh, zb);
        }
        k_update<<<ROWS / 4, blk, 0, stream>>>(zb, v, vb, vT);
    }
    k_readout<<<ROWS, blk, 0, stream>>>(v, ro, out);
}

// Round 8
// 5416.311 us; speedup vs baseline: 2.3227x; 1.1277x over previous
//
#include <hip/hip_runtime.h>
#include <hip/hip_fp16.h>
#include <math.h>

// ---------------- problem constants ----------------
#define D_     256
#define H_     4
#define NH     8192      // N / H
#define NTOT   32768
#define T_     1024
#define B_     2
#define ROWS   2048      // B * T
#define VOCAB_ 256
#define LAYERS 6
#define EPS_   1e-5f

typedef _Float16 f16;
typedef __attribute__((ext_vector_type(8))) _Float16 f16x8;
typedef __attribute__((ext_vector_type(4))) float f32x4;

// ---------------- GEMM core: C = A (MxK) * Bt (NxK)^T ----------------
// 128x128 tile, BK=64, 256 threads = 4 waves in 2x2, each wave 64x64 via
// 4x4 frags of mfma_f32_16x16x32_f16. LDS padded +8 f16 (16B) per row.
#define BM 128
#define BN 128
#define BK 64
#define LDST (BK + 8)

#define EPI_F32       0   // plain f32 store
#define EPI_RELU      1   // relu -> f16
#define EPI_RELU_MUL  3   // relu * aux -> f16 (in-place safe: aux may == C)
#define EPI_F32_ATOM  4   // atomicAdd f32 (split-K)
#define EPI_RELU_ROPE 5   // relu -> f16 C; rope(relu) -> f16 aux (2nd output)

// rope on 8 packed f16 (4 pairs) with interleaved {cos,sin} f16 table vec
__device__ __forceinline__ uint4 rope8(uint4 xin, uint4 csin) {
    union U { uint4 v; f16 h[8]; };
    U x, cs, o;
    x.v = xin; cs.v = csin;
#pragma unroll
    for (int j = 0; j < 4; j++) {
        float x1 = (float)x.h[2 * j], x2 = (float)x.h[2 * j + 1];
        float c  = (float)cs.h[2 * j], s = (float)cs.h[2 * j + 1];
        o.h[2 * j]     = (f16)(x1 * c - x2 * s);
        o.h[2 * j + 1] = (f16)(x1 * s + x2 * c);
    }
    return o.v;
}

// ROPE: rope A and B tiles while staging (fallback path; A,B rows are t,s)
// ACVT: A is f32 (Sf); convert + strict-causal mask (col<row) while staging
template<int EPI, bool ROPE, bool ACVT>
__device__ __forceinline__ void gemm_core(
    const void* __restrict__ Av, int lda,
    const f16* __restrict__ Bt, int ldb,
    void* __restrict__ Cv, int ldc,
    int row0, int col0, int k0beg, int k_end,
    const f16* __restrict__ aux,
    const f16* __restrict__ cstab)
{
    __shared__ f16 As[BM * LDST];
    __shared__ f16 Bs[BN * LDST];

    const int tid  = threadIdx.x;
    const int lane = tid & 63;
    const int wid  = tid >> 6;
    const int wr   = (wid >> 1) * 64;
    const int wc   = (wid & 1) * 64;
    const int lr   = lane & 15;
    const int lk   = (lane >> 4) * 8;

    f32x4 acc[4][4];
#pragma unroll
    for (int m = 0; m < 4; m++)
#pragma unroll
        for (int n = 0; n < 4; n++) acc[m][n] = (f32x4){0.f, 0.f, 0.f, 0.f};

    for (int k0 = k0beg; k0 < k_end; k0 += BK) {
        // stage A and Bt tiles: 1024 16B-vectors each, 4 per thread
#pragma unroll
        for (int i = 0; i < 4; i++) {
            int v  = tid + i * 256;
            int r  = v >> 3;
            int c8 = (v & 7) << 3;
            uint4 av;
            if constexpr (ACVT) {
                const float* Af = (const float*)Av;
                size_t base = (size_t)(row0 + r) * lda + k0 + c8;
                float4 f0 = *(const float4*)(Af + base);
                float4 f1 = *(const float4*)(Af + base + 4);
                int colb = k0 + c8, row = row0 + r;
                float fv[8] = {f0.x, f0.y, f0.z, f0.w, f1.x, f1.y, f1.z, f1.w};
                union { uint4 v4; f16 h[8]; } u;
#pragma unroll
                for (int j = 0; j < 8; j++)
                    u.h[j] = (f16)((colb + j < row) ? fv[j] : 0.f);
                av = u.v4;
            } else {
                av = *(const uint4*)((const f16*)Av + (size_t)(row0 + r) * lda + k0 + c8);
                if constexpr (ROPE) {
                    int p = (k0 + c8) >> 1;
                    av = rope8(av, *(const uint4*)(cstab + ((size_t)(row0 + r) * 4096 + p) * 2));
                }
            }
            uint4 bv = *(const uint4*)(Bt + (size_t)(col0 + r) * ldb + k0 + c8);
            if constexpr (ROPE) {
                int p = (k0 + c8) >> 1;
                bv = rope8(bv, *(const uint4*)(cstab + ((size_t)(col0 + r) * 4096 + p) * 2));
            }
            *(uint4*)(&As[r * LDST + c8]) = av;
            *(uint4*)(&Bs[r * LDST + c8]) = bv;
        }
        __syncthreads();
#pragma unroll
        for (int kk = 0; kk < BK; kk += 32) {
            f16x8 af[4], bfr[4];
#pragma unroll
            for (int m = 0; m < 4; m++)
                af[m] = *(const f16x8*)(&As[(wr + m * 16 + lr) * LDST + kk + lk]);
#pragma unroll
            for (int n = 0; n < 4; n++)
                bfr[n] = *(const f16x8*)(&Bs[(wc + n * 16 + lr) * LDST + kk + lk]);
#pragma unroll
            for (int m = 0; m < 4; m++)
#pragma unroll
                for (int n = 0; n < 4; n++)
                    acc[m][n] = __builtin_amdgcn_mfma_f32_16x16x32_f16(
                        af[m], bfr[n], acc[m][n], 0, 0, 0);
        }
        __syncthreads();
    }

    // epilogue: C row = A row, C col = Bt row; col=lane&15, row=(lane>>4)*4+r
    const int rbase = (lane >> 4) * 4;
#pragma unroll
    for (int m = 0; m < 4; m++) {
#pragma unroll
        for (int n = 0; n < 4; n++) {
#pragma unroll
            for (int r = 0; r < 4; r++) {
                int row = row0 + wr + m * 16 + rbase + r;
                int col = col0 + wc + n * 16 + lr;
                float val = acc[m][n][r];
                size_t o = (size_t)row * ldc + col;
                if constexpr (EPI == EPI_F32) {
                    ((float*)Cv)[o] = val;
                } else if constexpr (EPI == EPI_RELU) {
                    ((f16*)Cv)[o] = (f16)(val > 0.f ? val : 0.f);
                } else if constexpr (EPI == EPI_RELU_MUL) {
                    float xv = (float)aux[o];
                    ((f16*)Cv)[o] = (f16)((val > 0.f ? val : 0.f) * xv);
                } else if constexpr (EPI == EPI_RELU_ROPE) {
                    // pair partner is the adjacent column = adjacent lane
                    float vr_ = val > 0.f ? val : 0.f;
                    float pr_ = __shfl_xor(vr_, 1);
                    int t = row & (T_ - 1);
                    int p = col >> 1;
                    union { unsigned u; f16 h[2]; } q;
                    q.u = *(const unsigned*)(cstab + ((size_t)t * 4096 + p) * 2);
                    float c = (float)q.h[0], s = (float)q.h[1];
                    // even col: r1 = x1*c - x2*s ; odd col: r2 = x1*s + x2*c
                    float ro_ = (col & 1) ? (pr_ * s + vr_ * c) : (vr_ * c - pr_ * s);
                    ((f16*)Cv)[o] = (f16)vr_;
                    ((f16*)aux)[o] = (f16)ro_;
                } else { // EPI_F32_ATOM
                    atomicAdd(((float*)Cv) + o, val);
                }
            }
        }
    }
}

// ---------------- GEMM wrappers (per-head streaming) ----------------
// x_h = relu(vb @ dxT_h^T); qr_h = rope(x_h) — both written in one epilogue
__global__ __launch_bounds__(256) void k_gemm_xr(const f16* __restrict__ vb,
                                                 const f16* __restrict__ dxTh,
                                                 f16* __restrict__ xh,
                                                 f16* __restrict__ qrh,
                                                 const f16* __restrict__ cstab)
{
    gemm_core<EPI_RELU_ROPE, false, false>(vb, D_, dxTh, D_, xh, NH,
                                           blockIdx.y * BM, blockIdx.x * BN,
                                           0, D_, qrh, cstab);
}

// fallback: x only (round-4 path)
__global__ __launch_bounds__(256) void k_gemm_x(const f16* __restrict__ vb,
                                                const f16* __restrict__ dxTh,
                                                f16* __restrict__ xh)
{
    gemm_core<EPI_RELU, false, false>(vb, D_, dxTh, D_, xh, NH,
                                      blockIdx.y * BM, blockIdx.x * BN,
                                      0, D_, nullptr, nullptr);
}

#define KSPLIT_S 8
// Sf += qr_h qr_h^T chunk; packed lower-tri grid + split-K, atomics (Path A)
__global__ __launch_bounds__(256) void k_gemm_s2(const f16* __restrict__ qrh,
                                                 float* __restrict__ Sf)
{
    int tb = blockIdx.x;              // b*36 + packed lower-tri tile index
    int b  = tb / 36, ti = tb % 36;
    int ty = 0;
    while ((ty + 1) * (ty + 2) / 2 <= ti) ty++;
    int tx = ti - ty * (ty + 1) / 2;  // tx <= ty
    int k0 = blockIdx.y * (NH / KSPLIT_S);
    const f16* Qb = qrh + (size_t)b * T_ * NH;
    gemm_core<EPI_F32_ATOM, false, false>(Qb, NH, Qb, NH,
                                          Sf + (size_t)b * T_ * T_, T_,
                                          ty * BM, tx * BN,
                                          k0, k0 + NH / KSPLIT_S, nullptr, nullptr);
}

// fallback: rope fused in staging (round-4 path)
__global__ __launch_bounds__(256) void k_gemm_s(const f16* __restrict__ xh,
                                                float* __restrict__ Sf,
                                                const f16* __restrict__ cstab)
{
    int tb = blockIdx.x;
    int b  = tb / 36, ti = tb % 36;
    int ty = 0;
    while ((ty + 1) * (ty + 2) / 2 <= ti) ty++;
    int tx = ti - ty * (ty + 1) / 2;
    int k0 = blockIdx.y * (NH / KSPLIT_S);
    const f16* Ab = xh + (size_t)b * T_ * NH;
    gemm_core<EPI_F32_ATOM, true, false>(Ab, NH, Ab, NH,
                                         Sf + (size_t)b * T_ * T_, T_,
                                         ty * BM, tx * BN,
                                         k0, k0 + NH / KSPLIT_S, nullptr, cstab);
}

// a_h = mask(Sf) @ v ; f32 A staged with fused cvt+mask; causal split-K
#define CH_A 128
__global__ __launch_bounds__(256) void k_gemm_a(const float* __restrict__ Sf,
                                                const f16* __restrict__ vT,
                                                float* __restrict__ ah)
{
    int b = blockIdx.z >> 3, kc = blockIdx.z & 7;
    int kend = (blockIdx.y + 1) * BM;   // rows t in this tile need only s < kend
    int k0 = kc * CH_A;
    if (k0 >= kend) return;
    gemm_core<EPI_F32_ATOM, false, true>(Sf + (size_t)b * T_ * T_, T_,
                                         vT + (size_t)b * D_ * T_, T_,
                                         ah + (size_t)b * T_ * D_, D_,
                                         blockIdx.y * BM, blockIdx.x * BN,
                                         k0, k0 + CH_A, nullptr, nullptr);
}

// y_h = relu(lnA_h @ dyT_h^T) * x_h, written IN-PLACE over x_h
__global__ __launch_bounds__(256) void k_gemm_y(const f16* __restrict__ lnAh,
                                                const f16* __restrict__ dyTh,
                                                f16* __restrict__ xh)
{
    gemm_core<EPI_RELU_MUL, false, false>(lnAh, D_, dyTh, D_, xh, NH,
                                          blockIdx.y * BM, blockIdx.x * BN,
                                          0, D_, xh, nullptr);
}

// zb += y_h @ enc_h  (split-K=16, f32 atomic accumulate across heads too)
#define KSPLIT_Z 16
__global__ __launch_bounds__(256) void k_gemm_z(const f16* __restrict__ yh,
                                                const f16* __restrict__ encTh,
                                                float* __restrict__ zb)
{
    int k0 = blockIdx.z * (NH / KSPLIT_Z);
    gemm_core<EPI_F32_ATOM, false, false>(yh, NH, encTh, NTOT, zb, D_,
                                          blockIdx.y * BM, blockIdx.x * BN,
                                          k0, k0 + NH / KSPLIT_Z, nullptr, nullptr);
}

// ---------------- elementwise / LN / transpose ----------------
__device__ __forceinline__ float wave_sum(float s) {
#pragma unroll
    for (int off = 32; off; off >>= 1) s += __shfl_xor(s, off);
    return s;
}

__device__ __forceinline__ float4 ln4(float4 x) {
    float m = wave_sum(x.x + x.y + x.z + x.w) * (1.f / 256.f);
    float d0 = x.x - m, d1 = x.y - m, d2 = x.z - m, d3 = x.w - m;
    float var = wave_sum(d0 * d0 + d1 * d1 + d2 * d2 + d3 * d3) * (1.f / 256.f);
    float rs = rsqrtf(var + EPS_);
    return make_float4(d0 * rs, d1 * rs, d2 * rs, d3 * rs);
}

__device__ __forceinline__ void store_v_row(float4 o, int row, int lane,
                                            float* v, f16* vb, f16* vT) {
    *(float4*)(v + (size_t)row * D_ + lane * 4) = o;
    union { unsigned long long u; f16 h[4]; } p;
    p.h[0] = (f16)o.x; p.h[1] = (f16)o.y; p.h[2] = (f16)o.z; p.h[3] = (f16)o.w;
    *(unsigned long long*)(vb + (size_t)row * D_ + lane * 4) = p.u;
    int b = row >> 10, t = row & (T_ - 1);
    f16* vtp = vT + ((size_t)b * D_ + lane * 4) * T_ + t;
    vtp[0] = p.h[0]; vtp[T_] = p.h[1]; vtp[2 * T_] = p.h[2]; vtp[3 * T_] = p.h[3];
}

__global__ __launch_bounds__(256) void k_embed_ln(const int* __restrict__ idx,
                                                  const float* __restrict__ wte,
                                                  float* __restrict__ v,
                                                  f16* __restrict__ vb,
                                                  f16* __restrict__ vT)
{
    int row = blockIdx.x * 4 + (threadIdx.x >> 6);
    int lane = threadIdx.x & 63;
    int tok = idx[row];
    float4 x = *(const float4*)(wte + (size_t)tok * D_ + lane * 4);
    store_v_row(ln4(x), row, lane, v, vb, vT);
}

__global__ __launch_bounds__(256) void k_ln_f16(const float* __restrict__ in,
                                                f16* __restrict__ out)
{
    int row = blockIdx.x * 4 + (threadIdx.x >> 6);
    int lane = threadIdx.x & 63;
    float4 x = *(const float4*)(in + (size_t)row * D_ + lane * 4);
    float4 o = ln4(x);
    union { unsigned long long u; f16 h[4]; } p;
    p.h[0] = (f16)o.x; p.h[1] = (f16)o.y; p.h[2] = (f16)o.z; p.h[3] = (f16)o.w;
    *(unsigned long long*)(out + (size_t)row * D_ + lane * 4) = p.u;
}

__global__ __launch_bounds__(256) void k_update(const float* __restrict__ z,
                                                float* __restrict__ v,
                                                f16* __restrict__ vb,
                                                f16* __restrict__ vT)
{
    int row = blockIdx.x * 4 + (threadIdx.x >> 6);
    int lane = threadIdx.x & 63;
    float4 zr = *(const float4*)(z + (size_t)row * D_ + lane * 4);
    float4 lz = ln4(zr);
    float4 vr = *(const float4*)(v + (size_t)row * D_ + lane * 4);
    float4 u = make_float4(vr.x + lz.x, vr.y + lz.y, vr.z + lz.z, vr.w + lz.w);
    store_v_row(ln4(u), row, lane, v, vb, vT);
}

// interleaved {cos,sin} f16 table: [T][4096 pairs][2]
__global__ __launch_bounds__(256) void k_tables(f16* __restrict__ cstab)
{
    int i = blockIdx.x * 256 + threadIdx.x;   // T_ * 4096 total
    int t = i >> 12;
    int f = i & 4095;
    float invf = expf(-(float)f * (9.210340371976184f / 4096.f));
    float s, c;
    sincosf((float)t * invf, &s, &c);
    cstab[2 * i]     = (f16)c;
    cstab[2 * i + 1] = (f16)s;
}

// in: f32 [R][C] (batched) -> out: f16 [C][R]
__global__ void k_transpose(const float* __restrict__ in, f16* __restrict__ out,
                            int R, int C, size_t inBatch, size_t outBatch)
{
    const float* ip = in + (size_t)blockIdx.z * inBatch;
    f16* op = out + (size_t)blockIdx.z * outBatch;
    __shared__ float tile[32][33];
    int c0 = blockIdx.x * 32, r0 = blockIdx.y * 32;
    int tx = threadIdx.x, ty = threadIdx.y;
#pragma unroll
    for (int i = 0; i < 32; i += 8)
        tile[ty + i][tx] = ip[(size_t)(r0 + ty + i) * C + c0 + tx];
    __syncthreads();
#pragma unroll
    for (int i = 0; i < 32; i += 8)
        op[(size_t)(c0 + ty + i) * R + r0 + tx] = (f16)tile[tx][ty + i];
}

__global__ __launch_bounds__(256) void k_readout(const float* __restrict__ v,
                                                 const float* __restrict__ ro,
                                                 float* __restrict__ out)
{
    int row = blockIdx.x;
    int tid = threadIdx.x;
    __shared__ float vr[D_];
    vr[tid] = v[(size_t)row * D_ + tid];
    __syncthreads();
    float acc = 0.f;
#pragma unroll 8
    for (int d = 0; d < D_; d++) acc += vr[d] * ro[(size_t)d * VOCAB_ + tid];
    out[(size_t)row * VOCAB_ + tid] = acc;
}

// diagnostic: encode ws_size into output if workspace is insufficient
__global__ void k_sentinel(float* out, float val) { out[0] = val; }

// ---------------- launch ----------------
extern "C" void kernel_launch(void* const* d_in, const int* in_sizes, int n_in,
                              void* d_out, int out_size, void* d_ws, size_t ws_size,
                              hipStream_t stream)
{
    const int*   idx = (const int*)d_in[0];
    const float* wte = (const float*)d_in[1];
    const float* enc = (const float*)d_in[2];
    const float* dx  = (const float*)d_in[3];
    const float* dy  = (const float*)d_in[4];
    const float* ro  = (const float*)d_in[5];
    float* out = (float*)d_out;

    char* base = (char*)d_ws;
    size_t off = 0;
    auto alloc = [&](size_t bytes) -> void* {
        off = (off + 255) & ~(size_t)255;
        void* r = base + off;
        off += bytes;
        return r;
    };

    f16*   dxT   = (f16*)  alloc((size_t)H_ * NH * D_ * 2);     // 16 MB
    f16*   dyT   = (f16*)  alloc((size_t)H_ * NH * D_ * 2);     // 16 MB
    f16*   encT  = (f16*)  alloc((size_t)D_ * NTOT * 2);        // 16 MB
    f16*   cstab = (f16*)  alloc((size_t)T_ * 4096 * 2 * 2);    // 16 MB
    float* v     = (float*)alloc((size_t)ROWS * D_ * 4);        //  2 MB
    f16*   vb    = (f16*)  alloc((size_t)ROWS * D_ * 2);        //  1 MB
    f16*   vT    = (f16*)  alloc((size_t)B_ * D_ * T_ * 2);     //  1 MB
    f16*   xh    = (f16*)  alloc((size_t)ROWS * NH * 2);        // 32 MB
    float* Sf    = (float*)alloc((size_t)B_ * T_ * T_ * 4);     //  8 MB
    float* ah    = (float*)alloc((size_t)ROWS * D_ * 4);        //  2 MB
    f16*   lnAh  = (f16*)  alloc((size_t)ROWS * D_ * 2);        //  1 MB
    float* zb    = (float*)alloc((size_t)ROWS * D_ * 4);        //  2 MB
    size_t off_small = off;            // ~113 MB: round-4 fallback footprint
    f16*   qrh   = (f16*)  alloc((size_t)ROWS * NH * 2);        // 32 MB -> ~145 MB
    const bool bigws = (off <= ws_size);

    if (off_small > ws_size) {
        k_sentinel<<<1, 1, 0, stream>>>(out, 10000.f + (float)(ws_size >> 20));
        return;
    }

    dim3 blk(256), tb(32, 8);

    k_transpose<<<dim3(NH / 32, D_ / 32, H_), tb, 0, stream>>>(
        dx, dxT, D_, NH, (size_t)D_ * NH, (size_t)NH * D_);
    k_transpose<<<dim3(NH / 32, D_ / 32, H_), tb, 0, stream>>>(
        dy, dyT, D_, NH, (size_t)D_ * NH, (size_t)NH * D_);
    k_transpose<<<dim3(D_ / 32, NTOT / 32, 1), tb, 0, stream>>>(
        enc, encT, NTOT, D_, 0, 0);
    k_tables<<<T_ * 4096 / 256, blk, 0, stream>>>(cstab);
    k_embed_ln<<<ROWS / 4, blk, 0, stream>>>(idx, wte, v, vb, vT);

    for (int l = 0; l < LAYERS; l++) {
        hipMemsetAsync(zb, 0, (size_t)ROWS * D_ * 4, stream);
        for (int h = 0; h < H_; h++) {
            const f16* dxTh  = dxT + (size_t)h * NH * D_;
            const f16* dyTh  = dyT + (size_t)h * NH * D_;
            const f16* encTh = encT + (size_t)h * NH;
            if (bigws) {
                k_gemm_xr<<<dim3(NH / BN, ROWS / BM), blk, 0, stream>>>(
                    vb, dxTh, xh, qrh, cstab);
                hipMemsetAsync(Sf, 0, (size_t)B_ * T_ * T_ * 4, stream);
                k_gemm_s2<<<dim3(36 * B_, KSPLIT_S), blk, 0, stream>>>(qrh, Sf);
            } else {
                k_gemm_x<<<dim3(NH / BN, ROWS / BM), blk, 0, stream>>>(vb, dxTh, xh);
                hipMemsetAsync(Sf, 0, (size_t)B_ * T_ * T_ * 4, stream);
                k_gemm_s<<<dim3(36 * B_, KSPLIT_S), blk, 0, stream>>>(xh, Sf, cstab);
            }
            hipMemsetAsync(ah, 0, (size_t)ROWS * D_ * 4, stream);
            k_gemm_a<<<dim3(D_ / BN, T_ / BM, B_ * 8), blk, 0, stream>>>(Sf, vT, ah);
            k_ln_f16<<<ROWS / 4, blk, 0, stream>>>(ah, lnAh);
            k_gemm_y<<<dim3(NH / BN, ROWS / BM), blk, 0, stream>>>(lnAh, dyTh, xh);
            k_gemm_z<<<dim3(D_ / BN, ROWS / BM, KSPLIT_Z), blk, 0, stream>>>(xh, encTh, zb);
        }
        k_update<<<ROWS / 4, blk, 0, stream>>>(zb, v, vb, vT);
    }
    k_readout<<<ROWS, blk, 0, stream>>>(v, ro, out);
}

// Round 10
// 4438.620 us; speedup vs baseline: 2.8344x; 1.2203x over previous
//
#include <hip/hip_runtime.h>
#include <hip/hip_fp16.h>
#include <math.h>

// ---------------- problem constants ----------------
#define D_     256
#define H_     4
#define NH     8192      // N / H
#define NTOT   32768
#define T_     1024
#define B_     2
#define ROWS   2048      // B * T
#define VOCAB_ 256
#define LAYERS 6
#define EPS_   1e-5f

typedef _Float16 f16;
typedef __attribute__((ext_vector_type(8))) _Float16 f16x8;
typedef __attribute__((ext_vector_type(4))) float f32x4;

// ---------------- GEMM core: C = A (MxK) * Bt (NxK)^T ----------------
// 128x128 tile, BK=64, 256 threads = 4 waves in 2x2, each wave 64x64 via
// 4x4 frags of mfma_f32_16x16x32_f16.
// Staging: per-operand template choice:
//   G?=true  -> global_load_lds width-16 into LINEAR [128][64] LDS with XOR
//               chunk swizzle (source pre-swizzled, read swizzled — rule #21)
//   G?=false -> reg-staged uint4 into padded [128][72] LDS (for transforms:
//               ACVT f32->f16+causal-mask, ROPE-in-staging fallback)
#define BM 128
#define BN 128
#define BK 64
#define LDST (BK + 8)

#define EPI_F32       0   // plain f32 store
#define EPI_RELU      1   // relu -> f16
#define EPI_RELU_MUL  3   // relu * aux -> f16 (in-place safe: aux may == C)
#define EPI_F32_ATOM  4   // atomicAdd f32 (split-K)
#define EPI_RELU_ROPE 5   // relu -> f16 C; rope(relu) -> f16 aux (2nd output)

// rope on 8 packed f16 (4 pairs) with interleaved {cos,sin} f16 table vec
__device__ __forceinline__ uint4 rope8(uint4 xin, uint4 csin) {
    union U { uint4 v; f16 h[8]; };
    U x, cs, o;
    x.v = xin; cs.v = csin;
#pragma unroll
    for (int j = 0; j < 4; j++) {
        float x1 = (float)x.h[2 * j], x2 = (float)x.h[2 * j + 1];
        float c  = (float)cs.h[2 * j], s = (float)cs.h[2 * j + 1];
        o.h[2 * j]     = (f16)(x1 * c - x2 * s);
        o.h[2 * j + 1] = (f16)(x1 * s + x2 * c);
    }
    return o.v;
}

template<int EPI, bool ROPE, bool ACVT, bool GA, bool GB>
__device__ __forceinline__ void gemm_core(
    const void* __restrict__ Av, int lda,
    const f16* __restrict__ Bt, int ldb,
    void* __restrict__ Cv, int ldc,
    int row0, int col0, int k0beg, int k_end,
    const f16* __restrict__ aux,
    const f16* __restrict__ cstab)
{
    constexpr int SA = GA ? BK : LDST;
    constexpr int SB = GB ? BK : LDST;
    __shared__ f16 As[BM * SA];
    __shared__ f16 Bs[BN * SB];

    const int tid  = threadIdx.x;
    const int lane = tid & 63;
    const int wid  = tid >> 6;
    const int wr   = (wid >> 1) * 64;
    const int wc   = (wid & 1) * 64;
    const int lr   = lane & 15;
    const int lk   = (lane >> 4) * 8;

    f32x4 acc[4][4];
#pragma unroll
    for (int m = 0; m < 4; m++)
#pragma unroll
        for (int n = 0; n < 4; n++) acc[m][n] = (f32x4){0.f, 0.f, 0.f, 0.f};

    for (int k0 = k0beg; k0 < k_end; k0 += BK) {
        // stage A and Bt tiles: 1024 16B-slots each, 4 per thread
#pragma unroll
        for (int i = 0; i < 4; i++) {
            int v  = tid + i * 256;
            int r  = v >> 3;
            // ---- A operand ----
            if constexpr (GA) {
                int cc = (((v & 7) ^ (r & 7)) << 3);   // pre-swizzled source chunk
                const f16* src = (const f16*)Av + (size_t)(row0 + r) * lda + k0 + cc;
                __builtin_amdgcn_global_load_lds(
                    (const __attribute__((address_space(1))) unsigned int*)src,
                    (__attribute__((address_space(3))) unsigned int*)(As + (size_t)(v & ~63) * 8),
                    16, 0, 0);
            } else {
                int c8 = (v & 7) << 3;
                uint4 av;
                if constexpr (ACVT) {
                    const float* Af = (const float*)Av;
                    size_t base = (size_t)(row0 + r) * lda + k0 + c8;
                    float4 f0 = *(const float4*)(Af + base);
                    float4 f1 = *(const float4*)(Af + base + 4);
                    int colb = k0 + c8, row = row0 + r;
                    float fv[8] = {f0.x, f0.y, f0.z, f0.w, f1.x, f1.y, f1.z, f1.w};
                    union { uint4 v4; f16 h[8]; } u;
#pragma unroll
                    for (int j = 0; j < 8; j++)
                        u.h[j] = (f16)((colb + j < row) ? fv[j] : 0.f);
                    av = u.v4;
                } else {
                    av = *(const uint4*)((const f16*)Av + (size_t)(row0 + r) * lda + k0 + c8);
                    if constexpr (ROPE) {
                        int p = (k0 + c8) >> 1;
                        av = rope8(av, *(const uint4*)(cstab + ((size_t)(row0 + r) * 4096 + p) * 2));
                    }
                }
                *(uint4*)(&As[r * SA + c8]) = av;
            }
            // ---- B operand ----
            if constexpr (GB) {
                int cc = (((v & 7) ^ (r & 7)) << 3);
                const f16* src = Bt + (size_t)(col0 + r) * ldb + k0 + cc;
                __builtin_amdgcn_global_load_lds(
                    (const __attribute__((address_space(1))) unsigned int*)src,
                    (__attribute__((address_space(3))) unsigned int*)(Bs + (size_t)(v & ~63) * 8),
                    16, 0, 0);
            } else {
                int c8 = (v & 7) << 3;
                uint4 bv = *(const uint4*)(Bt + (size_t)(col0 + r) * ldb + k0 + c8);
                if constexpr (ROPE) {
                    int p = (k0 + c8) >> 1;
                    bv = rope8(bv, *(const uint4*)(cstab + ((size_t)(col0 + r) * 4096 + p) * 2));
                }
                *(uint4*)(&Bs[r * SB + c8]) = bv;
            }
        }
        __syncthreads();
#pragma unroll
        for (int kk = 0; kk < BK; kk += 32) {
            f16x8 af[4], bfr[4];
#pragma unroll
            for (int m = 0; m < 4; m++) {
                int rr = wr + m * 16 + lr;
                int off;
                if constexpr (GA) off = ((((kk + lk) >> 3) ^ (rr & 7)) << 3);
                else               off = kk + lk;
                af[m] = *(const f16x8*)(&As[rr * SA + off]);
            }
#pragma unroll
            for (int n = 0; n < 4; n++) {
                int rr = wc + n * 16 + lr;
                int off;
                if constexpr (GB) off = ((((kk + lk) >> 3) ^ (rr & 7)) << 3);
                else               off = kk + lk;
                bfr[n] = *(const f16x8*)(&Bs[rr * SB + off]);
            }
#pragma unroll
            for (int m = 0; m < 4; m++)
#pragma unroll
                for (int n = 0; n < 4; n++)
                    acc[m][n] = __builtin_amdgcn_mfma_f32_16x16x32_f16(
                        af[m], bfr[n], acc[m][n], 0, 0, 0);
        }
        __syncthreads();
    }

    // epilogue: C row = A row, C col = Bt row; col=lane&15, row=(lane>>4)*4+r
    const int rbase = (lane >> 4) * 4;
#pragma unroll
    for (int m = 0; m < 4; m++) {
#pragma unroll
        for (int n = 0; n < 4; n++) {
#pragma unroll
            for (int r = 0; r < 4; r++) {
                int row = row0 + wr + m * 16 + rbase + r;
                int col = col0 + wc + n * 16 + lr;
                float val = acc[m][n][r];
                size_t o = (size_t)row * ldc + col;
                if constexpr (EPI == EPI_F32) {
                    ((float*)Cv)[o] = val;
                } else if constexpr (EPI == EPI_RELU) {
                    ((f16*)Cv)[o] = (f16)(val > 0.f ? val : 0.f);
                } else if constexpr (EPI == EPI_RELU_MUL) {
                    float xv = (float)aux[o];
                    ((f16*)Cv)[o] = (f16)((val > 0.f ? val : 0.f) * xv);
                } else if constexpr (EPI == EPI_RELU_ROPE) {
                    // pair partner is the adjacent column = adjacent lane
                    float vr_ = val > 0.f ? val : 0.f;
                    float pr_ = __shfl_xor(vr_, 1);
                    int t = row & (T_ - 1);
                    int p = col >> 1;
                    union { unsigned u; f16 h[2]; } q;
                    q.u = *(const unsigned*)(cstab + ((size_t)t * 4096 + p) * 2);
                    float c = (float)q.h[0], s = (float)q.h[1];
                    float ro_ = (col & 1) ? (pr_ * s + vr_ * c) : (vr_ * c - pr_ * s);
                    ((f16*)Cv)[o] = (f16)vr_;
                    ((f16*)aux)[o] = (f16)ro_;
                } else { // EPI_F32_ATOM
                    atomicAdd(((float*)Cv) + o, val);
                }
            }
        }
    }
}

// ---------------- GEMM wrappers (per-head streaming) ----------------
// x_h = relu(vb @ dxT_h^T); qr_h = rope(x_h) — both written in one epilogue
__global__ __launch_bounds__(256) void k_gemm_xr(const f16* __restrict__ vb,
                                                 const f16* __restrict__ dxTh,
                                                 f16* __restrict__ xh,
                                                 f16* __restrict__ qrh,
                                                 const f16* __restrict__ cstab)
{
    gemm_core<EPI_RELU_ROPE, false, false, true, true>(
        vb, D_, dxTh, D_, xh, NH,
        blockIdx.y * BM, blockIdx.x * BN, 0, D_, qrh, cstab);
}

// fallback: x only (round-4 path)
__global__ __launch_bounds__(256) void k_gemm_x(const f16* __restrict__ vb,
                                                const f16* __restrict__ dxTh,
                                                f16* __restrict__ xh)
{
    gemm_core<EPI_RELU, false, false, true, true>(
        vb, D_, dxTh, D_, xh, NH,
        blockIdx.y * BM, blockIdx.x * BN, 0, D_, nullptr, nullptr);
}

#define KSPLIT_S 8
// Sf += qr_h qr_h^T chunk; packed lower-tri grid + split-K, atomics
__global__ __launch_bounds__(256) void k_gemm_s2(const f16* __restrict__ qrh,
                                                 float* __restrict__ Sf)
{
    int tb = blockIdx.x;              // b*36 + packed lower-tri tile index
    int b  = tb / 36, ti = tb % 36;
    int ty = 0;
    while ((ty + 1) * (ty + 2) / 2 <= ti) ty++;
    int tx = ti - ty * (ty + 1) / 2;  // tx <= ty
    int k0 = blockIdx.y * (NH / KSPLIT_S);
    const f16* Qb = qrh + (size_t)b * T_ * NH;
    gemm_core<EPI_F32_ATOM, false, false, true, true>(
        Qb, NH, Qb, NH, Sf + (size_t)b * T_ * T_, T_,
        ty * BM, tx * BN, k0, k0 + NH / KSPLIT_S, nullptr, nullptr);
}

// fallback: rope fused in staging (round-4 path; reg-staged)
__global__ __launch_bounds__(256) void k_gemm_s(const f16* __restrict__ xh,
                                                float* __restrict__ Sf,
                                                const f16* __restrict__ cstab)
{
    int tb = blockIdx.x;
    int b  = tb / 36, ti = tb % 36;
    int ty = 0;
    while ((ty + 1) * (ty + 2) / 2 <= ti) ty++;
    int tx = ti - ty * (ty + 1) / 2;
    int k0 = blockIdx.y * (NH / KSPLIT_S);
    const f16* Ab = xh + (size_t)b * T_ * NH;
    gemm_core<EPI_F32_ATOM, true, false, false, false>(
        Ab, NH, Ab, NH, Sf + (size_t)b * T_ * T_, T_,
        ty * BM, tx * BN, k0, k0 + NH / KSPLIT_S, nullptr, cstab);
}

// a_h = mask(Sf) @ v ; f32 A reg-staged with fused cvt+mask; B via gload
#define CH_A 128
__global__ __launch_bounds__(256) void k_gemm_a(const float* __restrict__ Sf,
                                                const f16* __restrict__ vT,
                                                float* __restrict__ ah)
{
    int b = blockIdx.z >> 3, kc = blockIdx.z & 7;
    int kend = (blockIdx.y + 1) * BM;   // rows t in this tile need only s < kend
    int k0 = kc * CH_A;
    if (k0 >= kend) return;
    gemm_core<EPI_F32_ATOM, false, true, false, true>(
        Sf + (size_t)b * T_ * T_, T_, vT + (size_t)b * D_ * T_, T_,
        ah + (size_t)b * T_ * D_, D_,
        blockIdx.y * BM, blockIdx.x * BN, k0, k0 + CH_A, nullptr, nullptr);
}

// y_h = relu(lnA_h @ dyT_h^T) * x_h, written IN-PLACE over x_h
__global__ __launch_bounds__(256) void k_gemm_y(const f16* __restrict__ lnAh,
                                                const f16* __restrict__ dyTh,
                                                f16* __restrict__ xh)
{
    gemm_core<EPI_RELU_MUL, false, false, true, true>(
        lnAh, D_, dyTh, D_, xh, NH,
        blockIdx.y * BM, blockIdx.x * BN, 0, D_, xh, nullptr);
}

// zb += y_h @ enc_h  (split-K=16, f32 atomic accumulate across heads too)
#define KSPLIT_Z 16
__global__ __launch_bounds__(256) void k_gemm_z(const f16* __restrict__ yh,
                                                const f16* __restrict__ encTh,
                                                float* __restrict__ zb)
{
    int k0 = blockIdx.z * (NH / KSPLIT_Z);
    gemm_core<EPI_F32_ATOM, false, false, true, true>(
        yh, NH, encTh, NTOT, zb, D_,
        blockIdx.y * BM, blockIdx.x * BN, k0, k0 + NH / KSPLIT_Z, nullptr, nullptr);
}

// ---------------- elementwise / LN / transpose ----------------
__device__ __forceinline__ float wave_sum(float s) {
#pragma unroll
    for (int off = 32; off; off >>= 1) s += __shfl_xor(s, off);
    return s;
}

__device__ __forceinline__ float4 ln4(float4 x) {
    float m = wave_sum(x.x + x.y + x.z + x.w) * (1.f / 256.f);
    float d0 = x.x - m, d1 = x.y - m, d2 = x.z - m, d3 = x.w - m;
    float var = wave_sum(d0 * d0 + d1 * d1 + d2 * d2 + d3 * d3) * (1.f / 256.f);
    float rs = rsqrtf(var + EPS_);
    return make_float4(d0 * rs, d1 * rs, d2 * rs, d3 * rs);
}

__device__ __forceinline__ void store_v_row(float4 o, int row, int lane,
                                            float* v, f16* vb, f16* vT) {
    *(float4*)(v + (size_t)row * D_ + lane * 4) = o;
    union { unsigned long long u; f16 h[4]; } p;
    p.h[0] = (f16)o.x; p.h[1] = (f16)o.y; p.h[2] = (f16)o.z; p.h[3] = (f16)o.w;
    *(unsigned long long*)(vb + (size_t)row * D_ + lane * 4) = p.u;
    int b = row >> 10, t = row & (T_ - 1);
    f16* vtp = vT + ((size_t)b * D_ + lane * 4) * T_ + t;
    vtp[0] = p.h[0]; vtp[T_] = p.h[1]; vtp[2 * T_] = p.h[2]; vtp[3 * T_] = p.h[3];
}

__global__ __launch_bounds__(256) void k_embed_ln(const int* __restrict__ idx,
                                                  const float* __restrict__ wte,
                                                  float* __restrict__ v,
                                                  f16* __restrict__ vb,
                                                  f16* __restrict__ vT)
{
    int row = blockIdx.x * 4 + (threadIdx.x >> 6);
    int lane = threadIdx.x & 63;
    int tok = idx[row];
    float4 x = *(const float4*)(wte + (size_t)tok * D_ + lane * 4);
    store_v_row(ln4(x), row, lane, v, vb, vT);
}

__global__ __launch_bounds__(256) void k_ln_f16(const float* __restrict__ in,
                                                f16* __restrict__ out)
{
    int row = blockIdx.x * 4 + (threadIdx.x >> 6);
    int lane = threadIdx.x & 63;
    float4 x = *(const float4*)(in + (size_t)row * D_ + lane * 4);
    float4 o = ln4(x);
    union { unsigned long long u; f16 h[4]; } p;
    p.h[0] = (f16)o.x; p.h[1] = (f16)o.y; p.h[2] = (f16)o.z; p.h[3] = (f16)o.w;
    *(unsigned long long*)(out + (size_t)row * D_ + lane * 4) = p.u;
}

__global__ __launch_bounds__(256) void k_update(const float* __restrict__ z,
                                                float* __restrict__ v,
                                                f16* __restrict__ vb,
                                                f16* __restrict__ vT)
{
    int row = blockIdx.x * 4 + (threadIdx.x >> 6);
    int lane = threadIdx.x & 63;
    float4 zr = *(const float4*)(z + (size_t)row * D_ + lane * 4);
    float4 lz = ln4(zr);
    float4 vr = *(const float4*)(v + (size_t)row * D_ + lane * 4);
    float4 u = make_float4(vr.x + lz.x, vr.y + lz.y, vr.z + lz.z, vr.w + lz.w);
    store_v_row(ln4(u), row, lane, v, vb, vT);
}

// interleaved {cos,sin} f16 table: [T][4096 pairs][2]
__global__ __launch_bounds__(256) void k_tables(f16* __restrict__ cstab)
{
    int i = blockIdx.x * 256 + threadIdx.x;   // T_ * 4096 total
    int t = i >> 12;
    int f = i & 4095;
    float invf = expf(-(float)f * (9.210340371976184f / 4096.f));
    float s, c;
    sincosf((float)t * invf, &s, &c);
    cstab[2 * i]     = (f16)c;
    cstab[2 * i + 1] = (f16)s;
}

// in: f32 [R][C] (batched) -> out: f16 [C][R]
__global__ void k_transpose(const float* __restrict__ in, f16* __restrict__ out,
                            int R, int C, size_t inBatch, size_t outBatch)
{
    const float* ip = in + (size_t)blockIdx.z * inBatch;
    f16* op = out + (size_t)blockIdx.z * outBatch;
    __shared__ float tile[32][33];
    int c0 = blockIdx.x * 32, r0 = blockIdx.y * 32;
    int tx = threadIdx.x, ty = threadIdx.y;
#pragma unroll
    for (int i = 0; i < 32; i += 8)
        tile[ty + i][tx] = ip[(size_t)(r0 + ty + i) * C + c0 + tx];
    __syncthreads();
#pragma unroll
    for (int i = 0; i < 32; i += 8)
        op[(size_t)(c0 + ty + i) * R + r0 + tx] = (f16)tile[tx][ty + i];
}

__global__ __launch_bounds__(256) void k_readout(const float* __restrict__ v,
                                                 const float* __restrict__ ro,
                                                 float* __restrict__ out)
{
    int row = blockIdx.x;
    int tid = threadIdx.x;
    __shared__ float vr[D_];
    vr[tid] = v[(size_t)row * D_ + tid];
    __syncthreads();
    float acc = 0.f;
#pragma unroll 8
    for (int d = 0; d < D_; d++) acc += vr[d] * ro[(size_t)d * VOCAB_ + tid];
    out[(size_t)row * VOCAB_ + tid] = acc;
}

// diagnostic: encode ws_size into output if workspace is insufficient
__global__ void k_sentinel(float* out, float val) { out[0] = val; }

// ---------------- launch ----------------
extern "C" void kernel_launch(void* const* d_in, const int* in_sizes, int n_in,
                              void* d_out, int out_size, void* d_ws, size_t ws_size,
                              hipStream_t stream)
{
    const int*   idx = (const int*)d_in[0];
    const float* wte = (const float*)d_in[1];
    const float* enc = (const float*)d_in[2];
    const float* dx  = (const float*)d_in[3];
    const float* dy  = (const float*)d_in[4];
    const float* ro  = (const float*)d_in[5];
    float* out = (float*)d_out;

    char* base = (char*)d_ws;
    size_t off = 0;
    auto alloc = [&](size_t bytes) -> void* {
        off = (off + 255) & ~(size_t)255;
        void* r = base + off;
        off += bytes;
        return r;
    };

    f16*   dxT   = (f16*)  alloc((size_t)H_ * NH * D_ * 2);     // 16 MB
    f16*   dyT   = (f16*)  alloc((size_t)H_ * NH * D_ * 2);     // 16 MB
    f16*   encT  = (f16*)  alloc((size_t)D_ * NTOT * 2);        // 16 MB
    f16*   cstab = (f16*)  alloc((size_t)T_ * 4096 * 2 * 2);    // 16 MB
    float* v     = (float*)alloc((size_t)ROWS * D_ * 4);        //  2 MB
    f16*   vb    = (f16*)  alloc((size_t)ROWS * D_ * 2);        //  1 MB
    f16*   vT    = (f16*)  alloc((size_t)B_ * D_ * T_ * 2);     //  1 MB
    f16*   xh    = (f16*)  alloc((size_t)ROWS * NH * 2);        // 32 MB
    float* Sf    = (float*)alloc((size_t)B_ * T_ * T_ * 4);     //  8 MB
    float* ah    = (float*)alloc((size_t)ROWS * D_ * 4);        //  2 MB
    f16*   lnAh  = (f16*)  alloc((size_t)ROWS * D_ * 2);        //  1 MB
    float* zb    = (float*)alloc((size_t)ROWS * D_ * 4);        //  2 MB
    size_t off_small = off;            // ~113 MB: round-4 fallback footprint
    f16*   qrh   = (f16*)  alloc((size_t)ROWS * NH * 2);        // 32 MB -> ~145 MB
    const bool bigws = (off <= ws_size);

    if (off_small > ws_size) {
        k_sentinel<<<1, 1, 0, stream>>>(out, 10000.f + (float)(ws_size >> 20));
        return;
    }

    dim3 blk(256), tb(32, 8);

    k_transpose<<<dim3(NH / 32, D_ / 32, H_), tb, 0, stream>>>(
        dx, dxT, D_, NH, (size_t)D_ * NH, (size_t)NH * D_);
    k_transpose<<<dim3(NH / 32, D_ / 32, H_), tb, 0, stream>>>(
        dy, dyT, D_, NH, (size_t)D_ * NH, (size_t)NH * D_);
    k_transpose<<<dim3(D_ / 32, NTOT / 32, 1), tb, 0, stream>>>(
        enc, encT, NTOT, D_, 0, 0);
    k_tables<<<T_ * 4096 / 256, blk, 0, stream>>>(cstab);
    k_embed_ln<<<ROWS / 4, blk, 0, stream>>>(idx, wte, v, vb, vT);

    for (int l = 0; l < LAYERS; l++) {
        hipMemsetAsync(zb, 0, (size_t)ROWS * D_ * 4, stream);
        for (int h = 0; h < H_; h++) {
            const f16* dxTh  = dxT + (size_t)h * NH * D_;
            const f16* dyTh  = dyT + (size_t)h * NH * D_;
            const f16* encTh = encT + (size_t)h * NH;
            if (bigws) {
                k_gemm_xr<<<dim3(NH / BN, ROWS / BM), blk, 0, stream>>>(
                    vb, dxTh, xh, qrh, cstab);
                hipMemsetAsync(Sf, 0, (size_t)B_ * T_ * T_ * 4, stream);
                k_gemm_s2<<<dim3(36 * B_, KSPLIT_S), blk, 0, stream>>>(qrh, Sf);
            } else {
                k_gemm_x<<<dim3(NH / BN, ROWS / BM), blk, 0, stream>>>(vb, dxTh, xh);
                hipMemsetAsync(Sf, 0, (size_t)B_ * T_ * T_ * 4, stream);
                k_gemm_s<<<dim3(36 * B_, KSPLIT_S), blk, 0, stream>>>(xh, Sf, cstab);
            }
            hipMemsetAsync(ah, 0, (size_t)ROWS * D_ * 4, stream);
            k_gemm_a<<<dim3(D_ / BN, T_ / BM, B_ * 8), blk, 0, stream>>>(Sf, vT, ah);
            k_ln_f16<<<ROWS / 4, blk, 0, stream>>>(ah, lnAh);
            k_gemm_y<<<dim3(NH / BN, ROWS / BM), blk, 0, stream>>>(lnAh, dyTh, xh);
            k_gemm_z<<<dim3(D_ / BN, ROWS / BM, KSPLIT_Z), blk, 0, stream>>>(xh, encTh, zb);
        }
        k_update<<<ROWS / 4, blk, 0, stream>>>(zb, v, vb, vT);
    }
    k_readout<<<ROWS, blk, 0, stream>>>(v, ro, out);
}